// Round 7
// baseline (686.279 us; speedup 1.0000x reference)
//
#include <hip/hip_runtime.h>
#include <hip/hip_bf16.h>

typedef __attribute__((ext_vector_type(4))) float floatx4;
typedef __attribute__((ext_vector_type(8))) __bf16 bf16x8;
typedef unsigned short ushort_t;

#define NENT  700
#define EMB   256
#define KDIM  1024
#define NDIM  512
#define HROWS 712   // 89*8: every row written by hab_kernel
#define NPAIR 340000

// ws byte offsets — total ~7.4 MB
#define WS_HA   0
#define WS_HB   (WS_HA + HROWS*KDIM*2)
#define WS_W2H  (WS_HB + HROWS*KDIM*2)
#define WS_ENT  (WS_W2H + NDIM*KDIM*2)
#define WS_LG   (WS_ENT + NENT*EMB*4)
#define WS_FLAG (WS_LG + NPAIR*2*4)

#if defined(__has_builtin)
#if __has_builtin(__builtin_amdgcn_global_load_lds)
#define USE_GLL 1
#endif
#endif

__device__ __forceinline__ float ldin(const void* p, int i, int isbf) {
    return isbf ? __bfloat162float(((const __hip_bfloat16*)p)[i])
                : ((const float*)p)[i];
}

// ---------------- stage 0: detect input dtype (f32 vs bf16), 1 wave ----------------
__global__ void detect_kernel(const ushort_t* __restrict__ w, int* __restrict__ flag) {
    int t = threadIdx.x;
    int e = (w[2*t] >> 7) & 0xFF;
    unsigned long long m = __ballot(e >= 100 && e <= 126);
    if (t == 0) *flag = (__popcll(m) >= 48) ? 1 : 0;
}

// ---------------- stage 1: ent = E @ W_ent, 8 rows/block ----------------
__global__ void ent_kernel(const void* __restrict__ E, const void* __restrict__ Went,
                           const int* __restrict__ flag,
                           float* __restrict__ ent, void* __restrict__ out) {
    int ib = blockIdx.x * 8, t = threadIdx.x;
    int isbf = *flag;
    __shared__ float rows[8][EMB];
#pragma unroll
    for (int r = 0; r < 8; ++r) {
        int i = ib + r;
        rows[r][t] = (i < NENT) ? ldin(E, i*EMB + t, isbf) : 0.f;
    }
    __syncthreads();
    float acc[8] = {0.f,0.f,0.f,0.f,0.f,0.f,0.f,0.f};
    if (isbf) {
        const __hip_bfloat16* W = (const __hip_bfloat16*)Went;
        for (int k = 0; k < EMB; ++k) {
            float w = __bfloat162float(W[k*EMB + t]);
#pragma unroll
            for (int r = 0; r < 8; ++r) acc[r] += rows[r][k] * w;
        }
    } else {
        const float* W = (const float*)Went;
        for (int k = 0; k < EMB; ++k) {
            float w = W[k*EMB + t];
#pragma unroll
            for (int r = 0; r < 8; ++r) acc[r] += rows[r][k] * w;
        }
    }
#pragma unroll
    for (int r = 0; r < 8; ++r) {
        int i = ib + r;
        if (i < NENT) {
            ent[i*EMB + t] = acc[r];
            if (i < 200) {
                if (isbf) ((__hip_bfloat16*)out)[680000 + i*EMB + t] = __float2bfloat16(acc[r]);
                else      ((float*)out)[680000 + i*EMB + t] = acc[r];
            }
        }
    }
}

// ---------------- stage 2: HA = ent@W1[:256] + b1 ; HB = ent@W1[256:] (bf16 out) ----------------
__global__ void hab_kernel(const float* __restrict__ ent,
                           const void* __restrict__ W1, const void* __restrict__ b1,
                           const int* __restrict__ flag,
                           __hip_bfloat16* __restrict__ HA, __hip_bfloat16* __restrict__ HB) {
    int part = blockIdx.y;
    int ib = blockIdx.x * 8;
    int t = threadIdx.x;
    int isbf = *flag;
    __shared__ float rows[8][EMB];
#pragma unroll
    for (int r = 0; r < 8; ++r) {
        int i = ib + r;
        rows[r][t] = (i < NENT) ? ent[i*EMB + t] : 0.f;
    }
    __syncthreads();
    float acc[8][4];
#pragma unroll
    for (int r = 0; r < 8; ++r)
#pragma unroll
        for (int p = 0; p < 4; ++p) acc[r][p] = 0.f;

    int wbase = part*EMB*KDIM;
    if (isbf) {
        const __hip_bfloat16* W = (const __hip_bfloat16*)W1;
        for (int k = 0; k < EMB; ++k) {
            float w[4];
#pragma unroll
            for (int p = 0; p < 4; ++p) w[p] = __bfloat162float(W[wbase + k*KDIM + t + p*256]);
#pragma unroll
            for (int r = 0; r < 8; ++r) {
                float e = rows[r][k];
#pragma unroll
                for (int p = 0; p < 4; ++p) acc[r][p] += e * w[p];
            }
        }
    } else {
        const float* W = (const float*)W1;
        for (int k = 0; k < EMB; ++k) {
            float w[4];
#pragma unroll
            for (int p = 0; p < 4; ++p) w[p] = W[wbase + k*KDIM + t + p*256];
#pragma unroll
            for (int r = 0; r < 8; ++r) {
                float e = rows[r][k];
#pragma unroll
                for (int p = 0; p < 4; ++p) acc[r][p] += e * w[p];
            }
        }
    }
    __hip_bfloat16* HX = part ? HB : HA;
#pragma unroll
    for (int r = 0; r < 8; ++r) {
#pragma unroll
        for (int p = 0; p < 4; ++p) {
            int n = t + p*256;
            float v = acc[r][p];
            if (!part) v += ldin(b1, n, isbf);
            HX[(ib + r)*KDIM + n] = __float2bfloat16(v);
        }
    }
}

// ---------------- prep: W2H = W2 as per-(half,kc) 16KB LDS images ----------------
// elem index: ((half*32+kc)*16 + f)*512 + lane*8 + j
//   value = bf16(W2[(kc*32 + (lane>>4)*8 + j)*512 + half*256 + f*16 + (lane&15)])
__global__ void prep_kernel(const void* __restrict__ W2, const int* __restrict__ flag,
                            __hip_bfloat16* __restrict__ W2H) {
    int g = blockIdx.x*256 + threadIdx.x;     // 65536
    int lane = g & 63, f = (g >> 6) & 15, kc = (g >> 10) & 31, half = g >> 15;
    int l15 = lane & 15, quad = lane >> 4;
    int n = half*256 + f*16 + l15;
    int isbf = *flag;
    bf16x8 v;
#pragma unroll
    for (int j = 0; j < 8; ++j) {
        int k = kc*32 + quad*8 + j;
        v[j] = (__bf16)ldin(W2, k*NDIM + n, isbf);
    }
    *(bf16x8*)(W2H + (size_t)g*8) = v;
}

union U8 { bf16x8 v; unsigned u[4]; };

// relu(ha_bf16 + hb_f32) -> bf16 round-half-up, pair-packed
__device__ __forceinline__ bf16x8 mk_af2(bf16x8 ha, const float* hb) {
    U8 r;
#pragma unroll
    for (int j = 0; j < 4; ++j) {
        float x0 = fmaxf((float)ha[2*j]   + hb[2*j],   0.f);
        float x1 = fmaxf((float)ha[2*j+1] + hb[2*j+1], 0.f);
        unsigned u0 = __float_as_uint(x0) + 0x8000u;
        unsigned u1 = __float_as_uint(x1) + 0x8000u;
        r.u[j] = (u0 >> 16) | (u1 & 0xFFFF0000u);
    }
    return r.v;
}

#define MFMA(a, b, c) __builtin_amdgcn_mfma_f32_16x16x32_bf16((a), (b), (c), 0, 0, 0)

// ---------------- main: fused pair MLP, 512 thr, tile m128 x n256-half ----------------
// 8 waves = 2 m-waves x 4 n-waves; wave m64 x n64; acc 64 regs -> 16 waves/CU.
__global__ __launch_bounds__(512, 4) void pair_kernel(
        const ushort_t* __restrict__ HA, const ushort_t* __restrict__ HB,
        const ushort_t* __restrict__ W2H,
        const void* __restrict__ b2, const void* __restrict__ W3,
        const int* __restrict__ flag, float* __restrict__ Lg) {

    const int blkEnd[10] = {325,650,900,1150,1400,1725,2050,2297,2544,2791};
    const int aB[10]  = {0,0,0,0,200,200,200,550,400,400};
    const int bB[10]  = {200,0,400,550,400,200,0,0,200,0};
    const int NaT[10] = {200,200,200,200,200,200,200,150,150,150};
    const int NbT[10] = {200,200,150,150,150,200,200,200,200,200};
    const int jTl[10] = {13,13,10,10,10,13,13,13,13,13};
    const int oOf[10] = {0,80000,160000,220000,280000,340000,420000,500000,560000,620000};

    __shared__ __align__(16) unsigned char smem[81920];
    char* sB  = (char*)smem;            // 2 x 16 KB ping-pong B chunks
    char* sHA = (char*)smem + 32768;    // 8 rows x 1024 k bf16 (2048 B/row)
    char* sHB = (char*)smem + 49152;    // 16 rows x 1024 k bf16, XOR-swizzled 16B granules

    int bid = blockIdx.x;
    int half = blockIdx.y;
    int ty = 0;
    while (bid >= blkEnd[ty]) ty++;
    int lb = bid - (ty ? blkEnd[ty-1] : 0);
    int jT = jTl[ty];
    int it = lb / jT;
    int jt = lb - it*jT;
    int i0 = aB[ty] + it*8;
    int j0 = bB[ty] + jt*16;

    int tid  = threadIdx.x;
    int lane = tid & 63;
    int w    = tid >> 6;       // 0..7
    int wm   = w & 1;          // m-wave: i-rows wm*4..wm*4+3
    int wn   = w >> 1;         // n-wave: 64-n slice of the 256-half
    int l15  = lane & 15;
    int quad = lane >> 4;
    int isbf = *flag;

    const char* Wbase = (const char*)W2H + ((size_t)(half*32))*16384;

    // prime: async-stage B chunk 0 into buffer 0
#ifdef USE_GLL
    __builtin_amdgcn_global_load_lds(
        (const __attribute__((address_space(1))) unsigned int*)(Wbase + w*1024 + lane*16),
        (__attribute__((address_space(3))) unsigned int*)(sB + w*1024), 16, 0, 0);
    __builtin_amdgcn_global_load_lds(
        (const __attribute__((address_space(1))) unsigned int*)(Wbase + (w+8)*1024 + lane*16),
        (__attribute__((address_space(3))) unsigned int*)(sB + (w+8)*1024), 16, 0, 0);
#else
    {
        uint4 t0 = *(const uint4*)(Wbase + w*1024 + lane*16);
        uint4 t1 = *(const uint4*)(Wbase + (w+8)*1024 + lane*16);
        *(uint4*)(sB + w*1024 + lane*16) = t0;
        *(uint4*)(sB + (w+8)*1024 + lane*16) = t1;
    }
#endif

    // stage sHA (8 rows, linear granules)
#pragma unroll
    for (int ii = 0; ii < 2; ++ii) {
        int idx = tid + ii*512;            // 1024 granules
        int r = idx >> 7, g = idx & 127;
        *(bf16x8*)(sHA + r*2048 + g*16) = *(const bf16x8*)(HA + (i0 + r)*KDIM + g*8);
    }
    // stage sHB (16 rows, granule g stored at g^(r&7))
#pragma unroll
    for (int ii = 0; ii < 4; ++ii) {
        int idx = tid + ii*512;            // 2048 granules
        int r = idx >> 7, g = idx & 127;
        *(bf16x8*)(sHB + r*2048 + ((g ^ (r & 7)) << 4)) = *(const bf16x8*)(HB + (j0 + r)*KDIM + g*8);
    }
    __syncthreads();   // drains async B loads too

    floatx4 acc[4][4];   // [f = m-frag][nf]
#pragma unroll
    for (int f = 0; f < 4; ++f)
#pragma unroll
        for (int nf = 0; nf < 4; ++nf) acc[f][nf] = (floatx4){0.f,0.f,0.f,0.f};

#pragma unroll 2
    for (int kc = 0; kc < 32; ++kc) {
        int buf = kc & 1;
        if (kc < 31) {
            const char* gsrc = Wbase + ((size_t)(kc + 1))*16384;
            char* ldst = sB + (buf ^ 1)*16384;
#ifdef USE_GLL
            __builtin_amdgcn_global_load_lds(
                (const __attribute__((address_space(1))) unsigned int*)(gsrc + w*1024 + lane*16),
                (__attribute__((address_space(3))) unsigned int*)(ldst + w*1024), 16, 0, 0);
            __builtin_amdgcn_global_load_lds(
                (const __attribute__((address_space(1))) unsigned int*)(gsrc + (w+8)*1024 + lane*16),
                (__attribute__((address_space(3))) unsigned int*)(ldst + (w+8)*1024), 16, 0, 0);
#else
            uint4 t0 = *(const uint4*)(gsrc + w*1024 + lane*16);
            uint4 t1 = *(const uint4*)(gsrc + (w+8)*1024 + lane*16);
            *(uint4*)(ldst + w*1024 + lane*16) = t0;
            *(uint4*)(ldst + (w+8)*1024 + lane*16) = t1;
#endif
        }

        // A-gen: hb (per-lane row l15, swizzled), ha (broadcast row per frag)
        bf16x8 hbv = *(const bf16x8*)(sHB + l15*2048 + (((kc*4 + quad) ^ (l15 & 7)) << 4));
        float hb[8];
#pragma unroll
        for (int j = 0; j < 8; ++j) hb[j] = (float)hbv[j];
        bf16x8 af[4];
#pragma unroll
        for (int f = 0; f < 4; ++f) {
            bf16x8 hav = *(const bf16x8*)(sHA + (wm*4 + f)*2048 + kc*64 + quad*16);
            af[f] = mk_af2(hav, hb);
        }
        // B frags (frag-contiguous, conflict-free)
        const char* sBb = sB + buf*16384;
        bf16x8 bfr[4];
#pragma unroll
        for (int nf = 0; nf < 4; ++nf)
            bfr[nf] = *(const bf16x8*)(sBb + (wn*4 + nf)*1024 + lane*16);
#pragma unroll
        for (int nf = 0; nf < 4; ++nf)
#pragma unroll
            for (int f = 0; f < 4; ++f)
                acc[f][nf] = MFMA(af[f], bfr[nf], acc[f][nf]);
        __syncthreads();
    }

    // epilogue: h2 = relu(acc + b2); partial logits over this wave's n64; atomic combine
    int nb = half*256 + wn*64;
    float b2v[4], wa[4], wb[4];
#pragma unroll
    for (int nf = 0; nf < 4; ++nf) {
        int n = nb + nf*16 + l15;
        b2v[nf] = ldin(b2, n, isbf);
        wa[nf]  = ldin(W3, 2*n, isbf);
        wb[nf]  = ldin(W3, 2*n+1, isbf);
    }
#pragma unroll
    for (int f = 0; f < 4; ++f) {
        float s0[4] = {0.f,0.f,0.f,0.f};
        float s1[4] = {0.f,0.f,0.f,0.f};
#pragma unroll
        for (int nf = 0; nf < 4; ++nf) {
            floatx4 c = acc[f][nf];
#pragma unroll
            for (int r = 0; r < 4; ++r) {
                float v = fmaxf(c[r] + b2v[nf], 0.f);
                s0[r] += v * wa[nf];
                s1[r] += v * wb[nf];
            }
        }
#pragma unroll
        for (int off = 1; off < 16; off <<= 1) {
#pragma unroll
            for (int r = 0; r < 4; ++r) {
                s0[r] += __shfl_xor(s0[r], off, 64);
                s1[r] += __shfl_xor(s1[r], off, 64);
            }
        }
        if (l15 == 0) {
            int pi = it*8 + wm*4 + f;
#pragma unroll
            for (int r = 0; r < 4; ++r) {
                int pj = jt*16 + quad*4 + r;
                if (pi < NaT[ty] && pj < NbT[ty]) {
                    int o = oOf[ty] + (pi*NbT[ty] + pj)*2;
                    atomicAdd(&Lg[o],   s0[r]);
                    atomicAdd(&Lg[o+1], s1[r]);
                }
            }
        }
    }
}

// ---------------- final: softmax over combined logits ----------------
__global__ void final_kernel(const float* __restrict__ Lg, const void* __restrict__ b3,
                             const int* __restrict__ flag, void* __restrict__ out) {
    int g = blockIdx.x*512 + threadIdx.x;
    if (g >= NPAIR) return;
    int isbf = *flag;
    float l0 = Lg[2*g]   + ldin(b3, 0, isbf);
    float l1 = Lg[2*g+1] + ldin(b3, 1, isbf);
    float mx = fmaxf(l0, l1);
    float e0 = __expf(l0 - mx), e1 = __expf(l1 - mx);
    float inv = 1.f / (e0 + e1);
    if (isbf) {
        __hip_bfloat16* ob = (__hip_bfloat16*)out;
        ob[2*g]   = __float2bfloat16(e0 * inv);
        ob[2*g+1] = __float2bfloat16(e1 * inv);
    } else {
        float* of = (float*)out;
        of[2*g]   = e0 * inv;
        of[2*g+1] = e1 * inv;
    }
}

extern "C" void kernel_launch(void* const* d_in, const int* in_sizes, int n_in,
                              void* d_out, int out_size, void* d_ws, size_t ws_size,
                              hipStream_t stream) {
    const void* E    = d_in[1];
    const void* Went = d_in[3];
    const void* W1   = d_in[5];
    const void* b1   = d_in[6];
    const void* W2   = d_in[7];
    const void* b2   = d_in[8];
    const void* W3   = d_in[9];
    const void* b3   = d_in[10];

    char* ws = (char*)d_ws;
    __hip_bfloat16* HA   = (__hip_bfloat16*)(ws + WS_HA);
    __hip_bfloat16* HB   = (__hip_bfloat16*)(ws + WS_HB);
    __hip_bfloat16* W2H  = (__hip_bfloat16*)(ws + WS_W2H);
    float*          entf = (float*)(ws + WS_ENT);
    float*          Lg   = (float*)(ws + WS_LG);
    int*            flag = (int*)(ws + WS_FLAG);

    detect_kernel<<<dim3(1), dim3(64), 0, stream>>>((const ushort_t*)E, flag);
    ent_kernel<<<dim3(88), dim3(256), 0, stream>>>(E, Went, flag, entf, d_out);
    hab_kernel<<<dim3(89, 2), dim3(256), 0, stream>>>(entf, W1, b1, flag, HA, HB);
    prep_kernel<<<dim3(256), dim3(256), 0, stream>>>(W2, flag, W2H);
    hipMemsetAsync(Lg, 0, NPAIR*2*sizeof(float), stream);
    pair_kernel<<<dim3(2791, 2), dim3(512), 0, stream>>>((const ushort_t*)HA, (const ushort_t*)HB,
                                                         (const ushort_t*)W2H, b2, W3, flag, Lg);
    final_kernel<<<dim3((NPAIR + 511)/512), dim3(512), 0, stream>>>(Lg, b3, flag, d_out);
}

// Round 8
// 568.636 us; speedup vs baseline: 1.2069x; 1.2069x over previous
//
#include <hip/hip_runtime.h>
#include <hip/hip_bf16.h>

typedef __attribute__((ext_vector_type(4))) float floatx4;
typedef __attribute__((ext_vector_type(8))) __bf16 bf16x8;
typedef unsigned short ushort_t;

#define NENT  700
#define EMB   256
#define KDIM  1024
#define NDIM  512
#define HROWS 712   // 89*8: every row written by hab_kernel
#define NPAIR 340000

// ws byte offsets — total ~7.4 MB (same footprint as R7, proven OK)
#define WS_HA   0
#define WS_HB   (WS_HA + HROWS*KDIM*2)
#define WS_W2H  (WS_HB + HROWS*KDIM*2)
#define WS_ENT  (WS_W2H + NDIM*KDIM*2)
#define WS_LG   (WS_ENT + NENT*EMB*4)
#define WS_FLAG (WS_LG + NPAIR*2*4)

__device__ __forceinline__ float ldin(const void* p, int i, int isbf) {
    return isbf ? __bfloat162float(((const __hip_bfloat16*)p)[i])
                : ((const float*)p)[i];
}

// ---------------- stage 0: detect input dtype (f32 vs bf16), 1 wave ----------------
__global__ void detect_kernel(const ushort_t* __restrict__ w, int* __restrict__ flag) {
    int t = threadIdx.x;
    int e = (w[2*t] >> 7) & 0xFF;
    unsigned long long m = __ballot(e >= 100 && e <= 126);
    if (t == 0) *flag = (__popcll(m) >= 48) ? 1 : 0;
}

// ---------------- stage 1: ent = E @ W_ent, 8 rows/block ----------------
__global__ void ent_kernel(const void* __restrict__ E, const void* __restrict__ Went,
                           const int* __restrict__ flag,
                           float* __restrict__ ent, void* __restrict__ out) {
    int ib = blockIdx.x * 8, t = threadIdx.x;
    int isbf = *flag;
    __shared__ float rows[8][EMB];
#pragma unroll
    for (int r = 0; r < 8; ++r) {
        int i = ib + r;
        rows[r][t] = (i < NENT) ? ldin(E, i*EMB + t, isbf) : 0.f;
    }
    __syncthreads();
    float acc[8] = {0.f,0.f,0.f,0.f,0.f,0.f,0.f,0.f};
    if (isbf) {
        const __hip_bfloat16* W = (const __hip_bfloat16*)Went;
        for (int k = 0; k < EMB; ++k) {
            float w = __bfloat162float(W[k*EMB + t]);
#pragma unroll
            for (int r = 0; r < 8; ++r) acc[r] += rows[r][k] * w;
        }
    } else {
        const float* W = (const float*)Went;
        for (int k = 0; k < EMB; ++k) {
            float w = W[k*EMB + t];
#pragma unroll
            for (int r = 0; r < 8; ++r) acc[r] += rows[r][k] * w;
        }
    }
#pragma unroll
    for (int r = 0; r < 8; ++r) {
        int i = ib + r;
        if (i < NENT) {
            ent[i*EMB + t] = acc[r];
            if (i < 200) {
                if (isbf) ((__hip_bfloat16*)out)[680000 + i*EMB + t] = __float2bfloat16(acc[r]);
                else      ((float*)out)[680000 + i*EMB + t] = acc[r];
            }
        }
    }
}

// ---------------- stage 2: HA = ent@W1[:256] + b1 ; HB = ent@W1[256:] (bf16 out) ----------------
__global__ void hab_kernel(const float* __restrict__ ent,
                           const void* __restrict__ W1, const void* __restrict__ b1,
                           const int* __restrict__ flag,
                           __hip_bfloat16* __restrict__ HA, __hip_bfloat16* __restrict__ HB) {
    int part = blockIdx.y;
    int ib = blockIdx.x * 8;
    int t = threadIdx.x;
    int isbf = *flag;
    __shared__ float rows[8][EMB];
#pragma unroll
    for (int r = 0; r < 8; ++r) {
        int i = ib + r;
        rows[r][t] = (i < NENT) ? ent[i*EMB + t] : 0.f;
    }
    __syncthreads();
    float acc[8][4];
#pragma unroll
    for (int r = 0; r < 8; ++r)
#pragma unroll
        for (int p = 0; p < 4; ++p) acc[r][p] = 0.f;

    int wbase = part*EMB*KDIM;
    if (isbf) {
        const __hip_bfloat16* W = (const __hip_bfloat16*)W1;
        for (int k = 0; k < EMB; ++k) {
            float w[4];
#pragma unroll
            for (int p = 0; p < 4; ++p) w[p] = __bfloat162float(W[wbase + k*KDIM + t + p*256]);
#pragma unroll
            for (int r = 0; r < 8; ++r) {
                float e = rows[r][k];
#pragma unroll
                for (int p = 0; p < 4; ++p) acc[r][p] += e * w[p];
            }
        }
    } else {
        const float* W = (const float*)W1;
        for (int k = 0; k < EMB; ++k) {
            float w[4];
#pragma unroll
            for (int p = 0; p < 4; ++p) w[p] = W[wbase + k*KDIM + t + p*256];
#pragma unroll
            for (int r = 0; r < 8; ++r) {
                float e = rows[r][k];
#pragma unroll
                for (int p = 0; p < 4; ++p) acc[r][p] += e * w[p];
            }
        }
    }
    __hip_bfloat16* HX = part ? HB : HA;
#pragma unroll
    for (int r = 0; r < 8; ++r) {
#pragma unroll
        for (int p = 0; p < 4; ++p) {
            int n = t + p*256;
            float v = acc[r][p];
            if (!part) v += ldin(b1, n, isbf);
            HX[(ib + r)*KDIM + n] = __float2bfloat16(v);
        }
    }
}

// ---------------- prep: W2H per-(half,kc) fragment-ordered images ----------------
// elem index: ((half*32+kc)*16 + f)*512 + lane*8 + j
//   = bf16(W2[(kc*32 + (lane>>4)*8 + j)*512 + half*256 + f*16 + (lane&15)])
__global__ void prep_kernel(const void* __restrict__ W2, const int* __restrict__ flag,
                            __hip_bfloat16* __restrict__ W2H) {
    int g = blockIdx.x*256 + threadIdx.x;     // 65536
    int lane = g & 63, f = (g >> 6) & 15, kc = (g >> 10) & 31, half = g >> 15;
    int l15 = lane & 15, quad = lane >> 4;
    int n = half*256 + f*16 + l15;
    int isbf = *flag;
    bf16x8 v;
#pragma unroll
    for (int j = 0; j < 8; ++j) {
        int k = kc*32 + quad*8 + j;
        v[j] = (__bf16)ldin(W2, k*NDIM + n, isbf);
    }
    *(bf16x8*)(W2H + (size_t)g*8) = v;
}

union U8 { bf16x8 v; unsigned u[4]; };

// relu(ha + hb) -> bf16 round-half-up, pair-packed (post-relu values >= 0)
__device__ __forceinline__ bf16x8 mk_af3(bf16x8 ha, bf16x8 hb) {
    U8 r;
#pragma unroll
    for (int j = 0; j < 4; ++j) {
        float x0 = fmaxf((float)ha[2*j]   + (float)hb[2*j],   0.f);
        float x1 = fmaxf((float)ha[2*j+1] + (float)hb[2*j+1], 0.f);
        unsigned u0 = __float_as_uint(x0) + 0x8000u;
        unsigned u1 = __float_as_uint(x1) + 0x8000u;
        r.u[j] = (u0 >> 16) | (u1 & 0xFFFF0000u);
    }
    return r.v;
}

#define MFMA(a, b, c) __builtin_amdgcn_mfma_f32_16x16x32_bf16((a), (b), (c), 0, 0, 0)

// ---------------- main: fused pair MLP ----------------
// 512 thr = 8 waves; block tile m128 pairs x n256 (half = blockIdx.y).
// Wave w: computes A-frag w (i-row i0+w, wave-uniform) -> sAF; MFMA tile m128 x n32.
// acc = 8x2x4 = 64 AGPR -> 2 blocks/CU (4 waves/SIMD). No atomics.
__global__ __launch_bounds__(512, 4) void pair_kernel(
        const ushort_t* __restrict__ HA, const ushort_t* __restrict__ HB,
        const ushort_t* __restrict__ W2H,
        const void* __restrict__ b2, const void* __restrict__ W3,
        const int* __restrict__ flag, float* __restrict__ Lg, void* __restrict__ out) {

    const int blkEnd[10] = {325,650,900,1150,1400,1725,2050,2297,2544,2791};
    const int aB[10]  = {0,0,0,0,200,200,200,550,400,400};
    const int bB[10]  = {200,0,400,550,400,200,0,0,200,0};
    const int NaT[10] = {200,200,200,200,200,200,200,150,150,150};
    const int NbT[10] = {200,200,150,150,150,200,200,200,200,200};
    const int jTl[10] = {13,13,10,10,10,13,13,13,13,13};
    const int oOf[10] = {0,80000,160000,220000,280000,340000,420000,500000,560000,620000};

    __shared__ __align__(16) unsigned char sAF[2*8192];   // A-frag double buffer
    __shared__ float lgt[8][128][2];                      // 8 KB partial logits

    int bid = blockIdx.x;
    int half = blockIdx.y;
    int ty = 0;
    while (bid >= blkEnd[ty]) ty++;
    int lb = bid - (ty ? blkEnd[ty-1] : 0);
    int jT = jTl[ty];
    int it = lb / jT;
    int jt = lb - it*jT;
    int i0 = aB[ty] + it*8;
    int j0 = bB[ty] + jt*16;

    int tid  = threadIdx.x;
    int lane = tid & 63;
    int w    = tid >> 6;       // 0..7: A-frag owner AND n32-slice owner
    int l15  = lane & 15;
    int quad = lane >> 4;
    int isbf = *flag;

    // pointers
    const char* WB = (const char*)W2H + ((size_t)((half*32)*16 + w*2))*1024 + lane*16;
    const ushort_t* HBp = HB + (j0 + l15)*KDIM + quad*8;   // per-lane hb row
    const ushort_t* HAp = HA + (i0 + w)*KDIM + quad*8;     // wave-uniform ha row

    floatx4 acc[8][2];
#pragma unroll
    for (int mf = 0; mf < 8; ++mf)
#pragma unroll
        for (int nf = 0; nf < 2; ++nf) acc[mf][nf] = (floatx4){0.f,0.f,0.f,0.f};

    // prime kc=0 operands
    bf16x8 B0 = *(const bf16x8*)(WB);
    bf16x8 B1 = *(const bf16x8*)(WB + 1024);
    bf16x8 hbv = *(const bf16x8*)(HBp);
    bf16x8 hav = *(const bf16x8*)(HAp);

    for (int kc = 0; kc < 32; ++kc) {
        int kcn = (kc + 1) & 31;   // wraps on last iter (harmless re-read)
        // distance-1 register prefetch (L2-hot)
        bf16x8 nB0 = *(const bf16x8*)(WB + (size_t)kcn*16384);
        bf16x8 nB1 = *(const bf16x8*)(WB + (size_t)kcn*16384 + 1024);
        bf16x8 nhb = *(const bf16x8*)(HBp + kcn*32);
        bf16x8 nha = *(const bf16x8*)(HAp + kcn*32);

        // A-gen: this wave's single fragment -> LDS
        bf16x8 afw = mk_af3(hav, hbv);
        *(bf16x8*)(sAF + (kc & 1)*8192 + w*1024 + lane*16) = afw;
        __syncthreads();

        // MFMA: all 8 m-frags x this wave's 2 n-frags, af in 2 batches of 4
        const unsigned char* sA = sAF + (kc & 1)*8192 + lane*16;
#pragma unroll
        for (int g = 0; g < 2; ++g) {
            bf16x8 af[4];
#pragma unroll
            for (int mf = 0; mf < 4; ++mf)
                af[mf] = *(const bf16x8*)(sA + (g*4 + mf)*1024);
#pragma unroll
            for (int mf = 0; mf < 4; ++mf) {
                acc[g*4+mf][0] = MFMA(af[mf], B0, acc[g*4+mf][0]);
                acc[g*4+mf][1] = MFMA(af[mf], B1, acc[g*4+mf][1]);
            }
        }
        B0 = nB0; B1 = nB1; hbv = nhb; hav = nha;
    }

    // epilogue: h2 = relu(acc + b2); partial logits over this wave's n32; LDS reduce
    int nb = half*256 + w*32;
    float b2v[2], wa[2], wb[2];
#pragma unroll
    for (int nf = 0; nf < 2; ++nf) {
        int n = nb + nf*16 + l15;
        b2v[nf] = ldin(b2, n, isbf);
        wa[nf]  = ldin(W3, 2*n, isbf);
        wb[nf]  = ldin(W3, 2*n+1, isbf);
    }
#pragma unroll
    for (int mf = 0; mf < 8; ++mf) {
        float s0[4] = {0.f,0.f,0.f,0.f};
        float s1[4] = {0.f,0.f,0.f,0.f};
#pragma unroll
        for (int nf = 0; nf < 2; ++nf) {
            floatx4 c = acc[mf][nf];
#pragma unroll
            for (int r = 0; r < 4; ++r) {
                float v = fmaxf(c[r] + b2v[nf], 0.f);
                s0[r] += v * wa[nf];
                s1[r] += v * wb[nf];
            }
        }
#pragma unroll
        for (int off = 1; off < 16; off <<= 1) {
#pragma unroll
            for (int r = 0; r < 4; ++r) {
                s0[r] += __shfl_xor(s0[r], off, 64);
                s1[r] += __shfl_xor(s1[r], off, 64);
            }
        }
        if (l15 == 0) {
#pragma unroll
            for (int r = 0; r < 4; ++r) {
                int p = mf*16 + quad*4 + r;
                lgt[w][p][0] = s0[r];
                lgt[w][p][1] = s1[r];
            }
        }
    }
    __syncthreads();

    if (tid < 128) {
        int p = tid;
        float l0 = 0.f, l1 = 0.f;
#pragma unroll
        for (int ww = 0; ww < 8; ++ww) { l0 += lgt[ww][p][0]; l1 += lgt[ww][p][1]; }
        int pi = it*8 + (p >> 4), pj = jt*16 + (p & 15);
        if (pi < NaT[ty] && pj < NbT[ty]) {
            int o = oOf[ty] + (pi*NbT[ty] + pj)*2;
            if (half == 0) {
                // exclusive owner of d_out slot: stash raw half-0 logits there
                if (isbf) {
                    __hip_bfloat16* ob = (__hip_bfloat16*)out;
                    ob[o] = __float2bfloat16(l0); ob[o+1] = __float2bfloat16(l1);
                } else {
                    float* of = (float*)out;
                    of[o] = l0; of[o+1] = l1;
                }
            } else {
                Lg[o] = l0; Lg[o+1] = l1;
            }
        }
    }
}

// ---------------- final: combine halves + b3, softmax, store ----------------
__global__ void final_kernel(const float* __restrict__ Lg, const void* __restrict__ b3,
                             const int* __restrict__ flag, void* __restrict__ out) {
    int g = blockIdx.x*512 + threadIdx.x;
    if (g >= NPAIR) return;
    int isbf = *flag;
    float h0, h1;
    if (isbf) {
        h0 = __bfloat162float(((const __hip_bfloat16*)out)[2*g]);
        h1 = __bfloat162float(((const __hip_bfloat16*)out)[2*g+1]);
    } else {
        h0 = ((const float*)out)[2*g];
        h1 = ((const float*)out)[2*g+1];
    }
    float l0 = h0 + Lg[2*g]   + ldin(b3, 0, isbf);
    float l1 = h1 + Lg[2*g+1] + ldin(b3, 1, isbf);
    float mx = fmaxf(l0, l1);
    float e0 = __expf(l0 - mx), e1 = __expf(l1 - mx);
    float inv = 1.f / (e0 + e1);
    if (isbf) {
        __hip_bfloat16* ob = (__hip_bfloat16*)out;
        ob[2*g]   = __float2bfloat16(e0 * inv);
        ob[2*g+1] = __float2bfloat16(e1 * inv);
    } else {
        float* of = (float*)out;
        of[2*g]   = e0 * inv;
        of[2*g+1] = e1 * inv;
    }
}

extern "C" void kernel_launch(void* const* d_in, const int* in_sizes, int n_in,
                              void* d_out, int out_size, void* d_ws, size_t ws_size,
                              hipStream_t stream) {
    const void* E    = d_in[1];
    const void* Went = d_in[3];
    const void* W1   = d_in[5];
    const void* b1   = d_in[6];
    const void* W2   = d_in[7];
    const void* b2   = d_in[8];
    const void* W3   = d_in[9];
    const void* b3   = d_in[10];

    char* ws = (char*)d_ws;
    __hip_bfloat16* HA   = (__hip_bfloat16*)(ws + WS_HA);
    __hip_bfloat16* HB   = (__hip_bfloat16*)(ws + WS_HB);
    __hip_bfloat16* W2H  = (__hip_bfloat16*)(ws + WS_W2H);
    float*          entf = (float*)(ws + WS_ENT);
    float*          Lg   = (float*)(ws + WS_LG);
    int*            flag = (int*)(ws + WS_FLAG);

    detect_kernel<<<dim3(1), dim3(64), 0, stream>>>((const ushort_t*)E, flag);
    ent_kernel<<<dim3(88), dim3(256), 0, stream>>>(E, Went, flag, entf, d_out);
    hab_kernel<<<dim3(89, 2), dim3(256), 0, stream>>>(entf, W1, b1, flag, HA, HB);
    prep_kernel<<<dim3(256), dim3(256), 0, stream>>>(W2, flag, W2H);
    pair_kernel<<<dim3(2791, 2), dim3(512), 0, stream>>>((const ushort_t*)HA, (const ushort_t*)HB,
                                                         (const ushort_t*)W2H, b2, W3, flag, Lg, d_out);
    final_kernel<<<dim3((NPAIR + 511)/512), dim3(512), 0, stream>>>(Lg, b3, flag, d_out);
}